// Round 9
// baseline (62384.070 us; speedup 1.0000x reference)
//
#include <hip/hip_runtime.h>
#include <cstdint>

constexpr int B = 32, ET = 1024, DT = 1024, D = 256, PAD = 15, PT = ET + 2*PAD;
constexpr float LOG2E = 1.4426950408889634f;

typedef __attribute__((ext_vector_type(4))) float f32x4;

// ws float layout
constexpr size_t PBUF_OFF = 0;                           // [B][2][PT] prev,cum (halo-padded)
constexpr size_t PART_OFF = PBUF_OFF + (size_t)B*2*PT;   // [B][16][D] att_out partials
constexpr size_t M_OFF    = PART_OFF + (size_t)B*16*D;   // [B][16] tile max
constexpr size_t S_OFF    = M_OFF + (size_t)B*16;        // [B][16] tile exp-sum
constexpr size_t WT2_OFF  = S_OFF + (size_t)B*16;        // [D][64] padded weights: [d][c*32+k]
constexpr size_t CNT_OFF  = WT2_OFF + (size_t)D*64;      // [B] uint barrier counters

__global__ __launch_bounds__(256) void k_init(const float* __restrict__ W,
                                              float* __restrict__ ws) {
  int i0 = blockIdx.x*256 + threadIdx.x;
  int stride = gridDim.x*256;
  for (int i = i0; i < B*2*PT; i += stride) ws[PBUF_OFF + i] = 0.f;
  for (int i = i0; i < B*16*D; i += stride) ws[PART_OFF + i] = 0.f;
  for (int i = i0; i < D*64; i += stride) {       // WT2[d][c*32+k] = W[d][c*31+k], pad k=31 -> 0
    int d = i >> 6, r = i & 63;
    int c = r >> 5, k = r & 31;
    ws[WT2_OFF + i] = (k < 31) ? W[d*62 + c*31 + k] : 0.f;
  }
  if (i0 < B) ((unsigned*)(ws + CNT_OFF))[i0] = 0u;
}

// relaxed agent-scope accessors: coherence-point loads/stores, no cache flushes
__device__ __forceinline__ float aload(const float* p) {
  return __hip_atomic_load(p, __ATOMIC_RELAXED, __HIP_MEMORY_SCOPE_AGENT);
}
__device__ __forceinline__ void astore(float* p, float v) {
  __hip_atomic_store(p, v, __ATOMIC_RELAXED, __HIP_MEMORY_SCOPE_AGENT);
}

// per-batch arrive-and-wait, 16 blocks, monotonic counter, zero fences.
__device__ __forceinline__ void batch_barrier(unsigned* cnt, unsigned target, int tid) {
  __syncthreads();
  if (tid == 0) {
    __hip_atomic_fetch_add(cnt, 1u, __ATOMIC_RELAXED, __HIP_MEMORY_SCOPE_AGENT);
    while (__hip_atomic_load(cnt, __ATOMIC_RELAXED, __HIP_MEMORY_SCOPE_AGENT) < target)
      __builtin_amdgcn_s_sleep(2);
  }
  __syncthreads();
}

// 16x s_load_dwordx4 (64 floats) + ONE waitcnt: a single L2 round-trip per d,
// values land in SGPRs via the scalar pipe.
#define SLOAD64(p, r0,r1,r2,r3,r4,r5,r6,r7,r8,r9,rA,rB,rC,rD,rE,rF)            \
  asm volatile("s_load_dwordx4 %0, %16, 0\n\t"                                 \
               "s_load_dwordx4 %1, %16, 16\n\t"                                \
               "s_load_dwordx4 %2, %16, 32\n\t"                                \
               "s_load_dwordx4 %3, %16, 48\n\t"                                \
               "s_load_dwordx4 %4, %16, 64\n\t"                                \
               "s_load_dwordx4 %5, %16, 80\n\t"                                \
               "s_load_dwordx4 %6, %16, 96\n\t"                                \
               "s_load_dwordx4 %7, %16, 112\n\t"                               \
               "s_load_dwordx4 %8, %16, 128\n\t"                               \
               "s_load_dwordx4 %9, %16, 144\n\t"                               \
               "s_load_dwordx4 %10, %16, 160\n\t"                              \
               "s_load_dwordx4 %11, %16, 176\n\t"                              \
               "s_load_dwordx4 %12, %16, 192\n\t"                              \
               "s_load_dwordx4 %13, %16, 208\n\t"                              \
               "s_load_dwordx4 %14, %16, 224\n\t"                              \
               "s_load_dwordx4 %15, %16, 240\n\t"                              \
               "s_waitcnt lgkmcnt(0)"                                          \
               : "=s"(r0),"=s"(r1),"=s"(r2),"=s"(r3),"=s"(r4),"=s"(r5),        \
                 "=s"(r6),"=s"(r7),"=s"(r8),"=s"(r9),"=s"(rA),"=s"(rB),        \
                 "=s"(rC),"=s"(rD),"=s"(rE),"=s"(rF)                           \
               : "s"(p))

#define WSEL(q0,q1,q2,q3,q4,q5,q6,q7,j)                                        \
  ((j) < 16 ? ((j) < 8 ? ((j) < 4 ? q0[(j)&3] : q1[(j)&3])                     \
                       : ((j) < 12 ? q2[(j)&3] : q3[(j)&3]))                   \
            : ((j) < 24 ? ((j) < 20 ? q4[(j)&3] : q5[(j)&3])                   \
                        : ((j) < 28 ? q6[(j)&3] : q7[(j)&3])))
#define WA(j) WSEL(w0,w1,w2,w3,w4,w5,w6,w7,(j))
#define WC(j) WSEL(w8,w9,wA,wB,wC,wD,wE,wF,(j))

__global__ __attribute__((amdgpu_flat_work_group_size(512, 512), amdgpu_waves_per_eu(4, 4)))
void k_decoder(
    const float* __restrict__ enc,   // [B][ET][D]
    const float* __restrict__ mel,   // [B][DT][D]
    const int* __restrict__ elen, const int* __restrict__ olen,
    const float* __restrict__ vw,    // [D]
    float* __restrict__ ws,
    float* __restrict__ out_att,     // [B][DT][D]
    float* __restrict__ out_sc) {    // [B][DT][ET]
  const int tid = threadIdx.x;
  const int lane = tid & 63;
  const int wq = __builtin_amdgcn_readfirstlane(tid >> 6);  // uniform wave id 0..7
  const int bid = blockIdx.x;
  const int xcd = bid & 7, slot = bid >> 3;
  const int b = ((slot & 3) << 3) | xcd;   // perf heuristic only (L2 locality)
  const int tile = slot >> 2;              // 0..15
  const int t0 = tile * 64;

  float* pbuf = ws + PBUF_OFF + (size_t)b*2*PT;
  float* part = ws + PART_OFF + (size_t)b*16*D;
  float* Mb   = ws + M_OFF + b*16;
  float* Sb   = ws + S_OFF + b*16;
  const float* WT2 = ws + WT2_OFF;
  unsigned* cnt = (unsigned*)(ws + CNT_OFF) + b;

  __shared__ float s_pa[96], s_pc[96], s_sc[64];
  __shared__ float s_uv[512];       // interleaved {u[d], v[d]}
  __shared__ float s_part[64][9];   // 8 wave partials per t, stride-9 pad
  __shared__ float s_ra[2][256];    // PV r-group partials

  const float vd = (tid < 256) ? vw[tid] : 0.f;
  const int L = elen[b];
  const int OL = olen[b];
  const float* wbase = WT2 + (size_t)wq * 32 * 64;   // wave's 32 weight rows

  unsigned target = 0;
#pragma unroll 1
  for (int step = 0; step < DT; ++step) {
    // -------- phase 1a: u(d) from part sums; stage p windows + u,v into LDS --------
    if (tid < 96) {
      int ix = t0 + tid; if (ix > PT-1) ix = PT-1;
      s_pa[tid] = aload(pbuf + ix);
      s_pc[tid] = aload(pbuf + PT + ix);
    }
    if (tid < 256) {
      float usum = 0.f;   // att_out(step-1), same summation order in every block
      const float* pp = part + tid;
#pragma unroll
      for (int j = 0; j < 16; ++j) usum += aload(pp + j*D);
      if (tile == 0 && step > 0) {
        float dmp = (step-1 < OL) ? 1.f : 0.f;
        out_att[((size_t)b*DT + step-1)*D + tid] = usum * dmp;
      }
      float dm = (step < OL) ? 1.f : 0.f;
      float ud = fmaf(mel[((size_t)b*DT + step)*D + tid], dm, usum); // u[d=tid]
      s_uv[2*tid] = ud;
      s_uv[2*tid+1] = vd;
    }
    __syncthreads();

    // -------- phase 1b: conv + tanh + v-dot; lane = t, d = wq*32 + i --------
    float shA[31], shC[31];   // shifted windows, 62 VGPRs, loaded once per step
#pragma unroll
    for (int k = 0; k < 31; ++k) { shA[k] = s_pa[lane + k]; shC[k] = s_pc[lane + k]; }

    float e_acc = 0.f;
#pragma unroll 1
    for (int i = 0; i < 32; ++i) {
      const float* wrow = wbase + i * 64;   // uniform
      f32x4 w0,w1,w2,w3,w4,w5,w6,w7,w8,w9,wA,wB,wC,wD,wE,wF;
      SLOAD64(wrow, w0,w1,w2,w3,w4,w5,w6,w7,w8,w9,wA,wB,wC,wD,wE,wF);
      const float2 uv = *(const float2*)&s_uv[2*(wq*32 + i)];  // uniform broadcast
      float s0 = uv.x, s1 = 0.f, s2 = 0.f, s3 = 0.f;  // 4 chains hide FMA latency
#pragma unroll
      for (int k = 0; k < 15; ++k) {
        s0 = fmaf(WA(2*k),   shA[2*k],   s0);
        s1 = fmaf(WA(2*k+1), shA[2*k+1], s1);
        s2 = fmaf(WC(2*k),   shC[2*k],   s2);
        s3 = fmaf(WC(2*k+1), shC[2*k+1], s3);
      }
      s0 = fmaf(WA(30), shA[30], s0);
      s2 = fmaf(WC(30), shC[30], s2);
      float s = (s0 + s1) + (s2 + s3);
      // tanh(s) = 1 - 2/(exp(2s)+1)
      float ex = __builtin_amdgcn_exp2f(s * (2.f*LOG2E));
      float th = fmaf(-2.f, __builtin_amdgcn_rcpf(ex + 1.f), 1.f);
      e_acc = fmaf(uv.y, th, e_acc);
    }
    s_part[lane][wq] = e_acc;
    __syncthreads();

    float e = 0.f;  // energy for t = t0+lane, stays in wave-0 regs across barrier
    if (tid < 64) {
      e = ((s_part[tid][0] + s_part[tid][1]) + (s_part[tid][2] + s_part[tid][3]))
        + ((s_part[tid][4] + s_part[tid][5]) + (s_part[tid][6] + s_part[tid][7]));
      float tmax = e;
#pragma unroll
      for (int msk = 1; msk < 64; msk <<= 1) tmax = fmaxf(tmax, __shfl_xor(tmax, msk, 64));
      float te = __builtin_amdgcn_exp2f((e - tmax) * LOG2E);
#pragma unroll
      for (int msk = 1; msk < 64; msk <<= 1) te += __shfl_xor(te, msk, 64);
      if (lane == 0) { astore(Mb + tile, tmax); astore(Sb + tile, te); }
    }
    target += 16;
    batch_barrier(cnt, target, tid);

    // -------- phase 2: global softmax, state update, att partials --------
    if (tid < 64) {
      float mj = aload(Mb + (lane & 15)), sj = aload(Sb + (lane & 15));
      float g = mj;
#pragma unroll
      for (int msk = 1; msk < 16; msk <<= 1) g = fmaxf(g, __shfl_xor(g, msk, 64));
      float z = sj * __builtin_amdgcn_exp2f((mj - g) * LOG2E);
#pragma unroll
      for (int msk = 1; msk < 16; msk <<= 1) z += __shfl_xor(z, msk, 64);
      float sc = __builtin_amdgcn_exp2f((e - g) * LOG2E) / z;
      int t = t0 + lane;
      if (t >= L) sc = 0.f;          // pad mask AFTER softmax (reference order)
      s_sc[lane] = sc;
      astore(pbuf + PAD + t, sc);                       // prev score
      float c = aload(pbuf + PT + PAD + t);             // cumulative (sole owner)
      astore(pbuf + PT + PAD + t, c + sc);
      out_sc[((size_t)b*DT + step)*ET + t] = sc;
    }
    __syncthreads();

    if (t0 < L) {   // tiles fully beyond elen keep part==0 (set by k_init)
      const int d = tid & 255, tg = tid >> 8;           // 2 r-groups of 32
      const float* eb = enc + ((size_t)b*ET + t0 + tg*32)*D + d;
      const float* scp = s_sc + tg*32;
      float a0 = 0.f, a1 = 0.f, a2 = 0.f, a3 = 0.f;
      for (int r = 0; r < 32; r += 4) {
        a0 = fmaf(scp[r],   eb[(size_t)r*D],     a0);
        a1 = fmaf(scp[r+1], eb[(size_t)(r+1)*D], a1);
        a2 = fmaf(scp[r+2], eb[(size_t)(r+2)*D], a2);
        a3 = fmaf(scp[r+3], eb[(size_t)(r+3)*D], a3);
      }
      s_ra[tg][d] = (a0 + a1) + (a2 + a3);
      __syncthreads();
      if (tid < 256) astore(part + tile*D + tid, s_ra[0][tid] + s_ra[1][tid]);
    }
    target += 16;
    batch_barrier(cnt, target, tid);
  }

  // epilogue: out_att for the final step
  if (tile == 0 && tid < 256) {
    float usum = 0.f;
    const float* pp = part + tid;
#pragma unroll
    for (int j = 0; j < 16; ++j) usum += aload(pp + j*D);
    float dmp = (DT-1 < OL) ? 1.f : 0.f;
    out_att[((size_t)b*DT + DT-1)*D + tid] = usum * dmp;
  }
}

extern "C" void kernel_launch(void* const* d_in, const int* in_sizes, int n_in,
                              void* d_out, int out_size, void* d_ws, size_t ws_size,
                              hipStream_t stream) {
  const float* enc = (const float*)d_in[0];
  const float* mel = (const float*)d_in[1];
  const int* elen  = (const int*)d_in[2];
  const int* olen  = (const int*)d_in[3];
  const float* vw  = (const float*)d_in[4];   // [1, D]
  const float* W   = (const float*)d_in[5];   // [D, 2, KW]

  float* out_att = (float*)d_out;                 // [B, DT, D]
  float* out_sc  = out_att + (size_t)B*DT*D;      // [B, DT, ET]
  float* ws = (float*)d_ws;

  k_init<<<128, 256, 0, stream>>>(W, ws);
  k_decoder<<<512, 512, 0, stream>>>(enc, mel, elen, olen, vw, ws, out_att, out_sc);
}

// Round 10
// 53860.870 us; speedup vs baseline: 1.1582x; 1.1582x over previous
//
#include <hip/hip_runtime.h>
#include <cstdint>

constexpr int B = 32, ET = 1024, DT = 1024, D = 256, PAD = 15, PT = ET + 2*PAD;
constexpr float LOG2E = 1.4426950408889634f;

// ws float layout
constexpr size_t PBUF_OFF = 0;                           // [B][2][PT] prev,cum (halo-padded)
constexpr size_t PART_OFF = PBUF_OFF + (size_t)B*2*PT;   // [B][16][D] att_out partials
constexpr size_t M_OFF    = PART_OFF + (size_t)B*16*D;   // [B][16] tile max
constexpr size_t S_OFF    = M_OFF + (size_t)B*16;        // [B][16] tile exp-sum
constexpr size_t WT_OFF   = S_OFF + (size_t)B*16;        // [62][D] transposed conv weights
constexpr size_t CNT_OFF  = WT_OFF + (size_t)62*D;       // [B] uint barrier counters

__global__ __launch_bounds__(256) void k_init(const float* __restrict__ W,
                                              float* __restrict__ ws) {
  int i0 = blockIdx.x*256 + threadIdx.x;
  int stride = gridDim.x*256;
  for (int i = i0; i < B*2*PT; i += stride) ws[PBUF_OFF + i] = 0.f;
  for (int i = i0; i < B*16*D; i += stride) ws[PART_OFF + i] = 0.f;
  for (int i = i0; i < 62*D; i += stride) {           // WT[k][d] = W[d][k]
    int k = i >> 8, d = i & 255;
    ws[WT_OFF + i] = W[d*62 + k];
  }
  if (i0 < B) ((unsigned*)(ws + CNT_OFF))[i0] = 0u;
}

template <int CTRL>
__device__ __forceinline__ float dpp_add(float x) {
  int y = __builtin_amdgcn_update_dpp(0, __float_as_int(x), CTRL, 0xF, 0xF, false);
  return x + __int_as_float(y);
}

// relaxed agent-scope accessors: coherence-point loads/stores, no cache flushes
__device__ __forceinline__ float aload(const float* p) {
  return __hip_atomic_load(p, __ATOMIC_RELAXED, __HIP_MEMORY_SCOPE_AGENT);
}
__device__ __forceinline__ void astore(float* p, float v) {
  __hip_atomic_store(p, v, __ATOMIC_RELAXED, __HIP_MEMORY_SCOPE_AGENT);
}

// per-batch arrive-and-wait, 16 blocks, monotonic counter, zero fences.
__device__ __forceinline__ void batch_barrier(unsigned* cnt, unsigned target, int tid) {
  __syncthreads();
  if (tid == 0) {
    __hip_atomic_fetch_add(cnt, 1u, __ATOMIC_RELAXED, __HIP_MEMORY_SCOPE_AGENT);
    while (__hip_atomic_load(cnt, __ATOMIC_RELAXED, __HIP_MEMORY_SCOPE_AGENT) < target)
      __builtin_amdgcn_s_sleep(2);
  }
  __syncthreads();
}

// wave-uniform float -> scalar register
__device__ __forceinline__ int rfl_f(float v) {
  return __builtin_amdgcn_readfirstlane(__float_as_int(v));
}

__global__ __attribute__((amdgpu_flat_work_group_size(256, 256), amdgpu_waves_per_eu(2, 2)))
void k_decoder(
    const float* __restrict__ enc,   // [B][ET][D]
    const float* __restrict__ mel,   // [B][DT][D]
    const int* __restrict__ elen, const int* __restrict__ olen,
    const float* __restrict__ vw,    // [D]
    float* __restrict__ ws,
    float* __restrict__ out_att,     // [B][DT][D]
    float* __restrict__ out_sc) {    // [B][DT][ET]
  const int tid = threadIdx.x;                              // d = tid
  const int lane = tid & 63;
  const int wq = __builtin_amdgcn_readfirstlane(tid >> 6);  // uniform wave id 0..3
  const int bid = blockIdx.x;
  const int xcd = bid & 7, slot = bid >> 3;
  const int b = ((slot & 3) << 3) | xcd;   // perf heuristic only (L2 locality)
  const int tile = slot >> 2;              // 0..15
  const int t0 = tile * 64;

  float* pbuf = ws + PBUF_OFF + (size_t)b*2*PT;
  float* part = ws + PART_OFF + (size_t)b*16*D;
  float* Mb   = ws + M_OFF + b*16;
  float* Sb   = ws + S_OFF + b*16;
  const float* WT = ws + WT_OFF;
  unsigned* cnt = (unsigned*)(ws + CNT_OFF) + b;

  __shared__ float s_w[62][256];    // step-invariant weights, staged once
  __shared__ float s_pa[96], s_pc[96], s_sc[64];
  __shared__ __align__(16) float s_part[64][20]; // 16 partials per t, padded row

  // stage weights into LDS once (coalesced; covered by first in-loop syncthreads)
#pragma unroll 1
  for (int k = 0; k < 62; ++k) s_w[k][tid] = WT[k*D + tid];

  const float vd  = vw[tid];
  const float m2v = -2.f * vd;      // y = v*tanh(s) = fma(m2v, rcp(exp2(2.885*s)+1), v)
  const int L = elen[b];
  const int OL = olen[b];

  unsigned target = 0;
#pragma unroll 1
  for (int step = 0; step < DT; ++step) {
    // -------- phase 1a: u(d=tid) from part sums; stage p windows into LDS --------
    float usum = 0.f;   // att_out(step-1), same summation order in every block
    {
      const float* pp = part + tid;
#pragma unroll
      for (int j = 0; j < 16; ++j) usum += aload(pp + j*D);
    }
    if (tid < 96) {
      int ix = t0 + tid; if (ix > PT-1) ix = PT-1;   // tail slots unused by math
      s_pa[tid] = aload(pbuf + ix);
      s_pc[tid] = aload(pbuf + PT + ix);
    }
    if (tile == 0 && step > 0) {
      float dmp = (step-1 < OL) ? 1.f : 0.f;
      out_att[((size_t)b*DT + step-1)*D + tid] = usum * dmp;
    }
    const float dm = (step < OL) ? 1.f : 0.f;
    const float ud = fmaf(mel[((size_t)b*DT + step)*D + tid], dm, usum); // u[d=tid]
    __syncthreads();

    // -------- phase 1b: conv + tanh + v-dot; lane = d, t sequential --------
    float wr[62];                    // per-lane weights, lifetime = this step
#pragma unroll
    for (int k = 0; k < 62; ++k) wr[k] = s_w[k][tid];

    // wave-uniform sliding window in SGPRs (circular, unroll-32 -> static idx)
    int swa[32], swc[32];
#pragma unroll
    for (int k = 0; k < 31; ++k) { swa[k] = rfl_f(s_pa[k]); swc[k] = rfl_f(s_pc[k]); }

#pragma unroll 1
    for (int tb = 0; tb < 64; tb += 32) {
#pragma unroll
      for (int m = 0; m < 32; ++m) {
        const int j = tb + m;
        float s0 = ud, s1 = 0.f, s2 = 0.f, s3 = 0.f;  // 4 chains hide FMA latency
#pragma unroll
        for (int k = 0; k < 15; ++k) {
          s0 = fmaf(wr[2*k],    __int_as_float(swa[(m+2*k)&31]),   s0);
          s1 = fmaf(wr[2*k+1],  __int_as_float(swa[(m+2*k+1)&31]), s1);
          s2 = fmaf(wr[31+2*k],   __int_as_float(swc[(m+2*k)&31]),   s2);
          s3 = fmaf(wr[31+2*k+1], __int_as_float(swc[(m+2*k+1)&31]), s3);
        }
        s0 = fmaf(wr[30], __int_as_float(swa[(m+30)&31]), s0);
        s2 = fmaf(wr[61], __int_as_float(swc[(m+30)&31]), s2);
        float s = (s0 + s1) + (s2 + s3);
        // y = v_d * tanh(s);  tanh(s) = 1 - 2/(exp(2s)+1)
        float ex = __builtin_amdgcn_exp2f(s * (2.f*LOG2E));
        float r  = __builtin_amdgcn_rcpf(ex + 1.f);
        float y  = fmaf(m2v, r, vd);
        y = dpp_add<0xB1>(y);   // + lane^1
        y = dpp_add<0x4E>(y);   // + lane^2
        y = dpp_add<0x141>(y);  // row_half_mirror (+^4 within 8)
        y = dpp_add<0x140>(y);  // row_mirror      (+^8 within 16)
        if ((lane & 15) == 0) s_part[j][(wq << 2) | (lane >> 4)] = y;
        // slide window: slot (m+31)&31 <- s_p*[j+31] (uniform broadcast + rfl)
        swa[(m+31)&31] = rfl_f(s_pa[j + 31]);
        swc[(m+31)&31] = rfl_f(s_pc[j + 31]);
      }
    }
    __syncthreads();

    float e = 0.f;  // energy for t = t0+lane, stays in wave-0 regs across barrier
    if (tid < 64) {
      const float4 r0 = *(const float4*)&s_part[tid][0];
      const float4 r1 = *(const float4*)&s_part[tid][4];
      const float4 r2 = *(const float4*)&s_part[tid][8];
      const float4 r3 = *(const float4*)&s_part[tid][12];
      e = (((r0.x+r0.y)+(r0.z+r0.w)) + ((r1.x+r1.y)+(r1.z+r1.w)))
        + (((r2.x+r2.y)+(r2.z+r2.w)) + ((r3.x+r3.y)+(r3.z+r3.w)));
      float tmax = e;
#pragma unroll
      for (int msk = 1; msk < 64; msk <<= 1) tmax = fmaxf(tmax, __shfl_xor(tmax, msk, 64));
      float te = __builtin_amdgcn_exp2f((e - tmax) * LOG2E);
#pragma unroll
      for (int msk = 1; msk < 64; msk <<= 1) te += __shfl_xor(te, msk, 64);
      if (lane == 0) { astore(Mb + tile, tmax); astore(Sb + tile, te); }
    }
    target += 16;
    batch_barrier(cnt, target, tid);

    // -------- phase 2: global softmax, state update, att partials --------
    if (tid < 64) {
      float mj = aload(Mb + (lane & 15)), sj = aload(Sb + (lane & 15));
      float g = mj;
#pragma unroll
      for (int msk = 1; msk < 16; msk <<= 1) g = fmaxf(g, __shfl_xor(g, msk, 64));
      float z = sj * __builtin_amdgcn_exp2f((mj - g) * LOG2E);
#pragma unroll
      for (int msk = 1; msk < 16; msk <<= 1) z += __shfl_xor(z, msk, 64);
      float sc = __builtin_amdgcn_exp2f((e - g) * LOG2E) / z;
      int t = t0 + lane;
      if (t >= L) sc = 0.f;          // pad mask AFTER softmax (reference order)
      s_sc[lane] = sc;
      astore(pbuf + PAD + t, sc);                       // prev score
      float c = aload(pbuf + PT + PAD + t);             // cumulative (sole owner)
      astore(pbuf + PT + PAD + t, c + sc);
      out_sc[((size_t)b*DT + step)*ET + t] = sc;
    }
    __syncthreads();

    if (t0 < L) {   // tiles fully beyond elen keep part==0 (set by k_init)
      const float* eb = enc + ((size_t)b*ET + t0)*D + tid;
      float a0 = 0.f, a1 = 0.f, a2 = 0.f, a3 = 0.f;
      for (int r = 0; r < 64; r += 4) {
        a0 = fmaf(s_sc[r],   eb[(size_t)r*D],     a0);
        a1 = fmaf(s_sc[r+1], eb[(size_t)(r+1)*D], a1);
        a2 = fmaf(s_sc[r+2], eb[(size_t)(r+2)*D], a2);
        a3 = fmaf(s_sc[r+3], eb[(size_t)(r+3)*D], a3);
      }
      astore(part + tile*D + tid, (a0 + a1) + (a2 + a3));
    }
    target += 16;
    batch_barrier(cnt, target, tid);
  }

  // epilogue: out_att for the final step
  if (tile == 0) {
    float usum = 0.f;
    const float* pp = part + tid;
#pragma unroll
    for (int j = 0; j < 16; ++j) usum += aload(pp + j*D);
    float dmp = (DT-1 < OL) ? 1.f : 0.f;
    out_att[((size_t)b*DT + DT-1)*D + tid] = usum * dmp;
  }
}

extern "C" void kernel_launch(void* const* d_in, const int* in_sizes, int n_in,
                              void* d_out, int out_size, void* d_ws, size_t ws_size,
                              hipStream_t stream) {
  const float* enc = (const float*)d_in[0];
  const float* mel = (const float*)d_in[1];
  const int* elen  = (const int*)d_in[2];
  const int* olen  = (const int*)d_in[3];
  const float* vw  = (const float*)d_in[4];   // [1, D]
  const float* W   = (const float*)d_in[5];   // [D, 2, KW]

  float* out_att = (float*)d_out;                 // [B, DT, D]
  float* out_sc  = out_att + (size_t)B*DT*D;      // [B, DT, ET]
  float* ws = (float*)d_ws;

  k_init<<<128, 256, 0, stream>>>(W, ws);
  k_decoder<<<512, 256, 0, stream>>>(enc, mel, elen, olen, vw, ws, out_att, out_sc);
}

// Round 11
// 25874.203 us; speedup vs baseline: 2.4111x; 2.0816x over previous
//
#include <hip/hip_runtime.h>
#include <cstdint>

constexpr int B = 32, ET = 1024, DT = 1024, D = 256, PAD = 15, PT = ET + 2*PAD;
constexpr float LOG2E = 1.4426950408889634f;

// ws float layout (double-buffered by step parity; NO atomics, NO barriers)
constexpr size_t PBUF_OFF = 0;                            // [B][2 par][2 ch][PT] ch0=raw, ch1=cum
constexpr size_t PART_OFF = PBUF_OFF + (size_t)B*4*PT;    // [B][2 par][16][D] raw PV partials
constexpr size_t SSUM_OFF = PART_OFF + (size_t)B*2*16*D;  // [B][2 par][16] raw tile sums
constexpr size_t WT_OFF   = SSUM_OFF + (size_t)B*2*16;    // [62][D] transposed conv weights

__global__ __launch_bounds__(256) void k_init(const float* __restrict__ W,
                                              float* __restrict__ ws) {
  int i0 = blockIdx.x*256 + threadIdx.x;
  int stride = gridDim.x*256;
  for (int i = i0; i < B*4*PT; i += stride) ws[PBUF_OFF + i] = 0.f;
  for (int i = i0; i < B*2*16*D; i += stride) ws[PART_OFF + i] = 0.f;
  for (int i = i0; i < B*2*16; i += stride) ws[SSUM_OFF + i] = 0.0625f;  // Z(step0)=1
  for (int i = i0; i < 62*D; i += stride) {            // WT[k][d] = W[d][k]
    int k = i >> 8, d = i & 255;
    ws[WT_OFF + i] = W[d*62 + k];
  }
}

template <int CTRL>
__device__ __forceinline__ float dpp_add(float x) {
  int y = __builtin_amdgcn_update_dpp(0, __float_as_int(x), CTRL, 0xF, 0xF, false);
  return x + __int_as_float(y);
}
__device__ __forceinline__ int rfl_f(float v) {
  return __builtin_amdgcn_readfirstlane(__float_as_int(v));
}

// One decoder step. Reads parity p state (published by step-1), writes parity p^1.
// Kernel boundary provides all cross-block synchronization.
__global__ __launch_bounds__(256) void k_step(
    const float* __restrict__ enc,   // [B][ET][D]
    const float* __restrict__ mel,   // [B][DT][D]
    const int* __restrict__ elen, const int* __restrict__ olen,
    const float* __restrict__ vw,    // [D]
    float* __restrict__ ws,
    float* __restrict__ out_att,     // [B][DT][D]
    float* __restrict__ out_sc,      // [B][DT][ET]
    int step) {
  const int tid = threadIdx.x;                              // d = tid
  const int lane = tid & 63;
  const int wq = __builtin_amdgcn_readfirstlane(tid >> 6);  // wave id 0..3
  const int bid = blockIdx.x;
  const int xcd = bid & 7, slot = bid >> 3;
  const int b = ((slot & 3) << 3) | xcd;   // L2-locality heuristic
  const int tile = slot >> 2;              // 0..15
  const int t0 = tile * 64;
  const int p = step & 1, np = p ^ 1;

  float* pb = ws + PBUF_OFF + (size_t)b*4*PT;
  const float* raw_p = pb + (size_t)(p*2 + 0)*PT;
  const float* cum_p = pb + (size_t)(p*2 + 1)*PT;
  float* raw_n = pb + (size_t)(np*2 + 0)*PT;
  float* cum_n = pb + (size_t)(np*2 + 1)*PT;
  const float* part_p = ws + PART_OFF + ((size_t)b*2 + p)*16*D;
  float*       part_n = ws + PART_OFF + ((size_t)b*2 + np)*16*D;
  const float* S_p = ws + SSUM_OFF + (b*2 + p)*16;
  float*       S_n = ws + SSUM_OFF + (b*2 + np)*16;
  const float* WT = ws + WT_OFF;

  __shared__ float s_pa[96], s_pc[96], s_sc[64];
  __shared__ __align__(16) float s_part[64][20];

  const int L = elen[b];
  const int OL = olen[b];
  const float vd  = vw[tid];
  const float m2v = -2.f * vd;     // sum_d v*tanh = sum_d (v + m2v*rcp(exp+1))

  // ---- normalization of step-1 state ----
  float z = 0.f;
#pragma unroll
  for (int j = 0; j < 16; ++j) z += S_p[j];
  const float Zinv = 1.f / z;

  // u[d=tid] = mel*dm + att_out(step-1);  att_out = (sum part~)/Z
  float usum = 0.f;
#pragma unroll
  for (int j = 0; j < 16; ++j) usum += part_p[j*D + tid];
  usum *= Zinv;
  if (tile == 0 && step > 0) {
    float dmp = (step-1 < OL) ? 1.f : 0.f;
    out_att[((size_t)b*DT + step-1)*D + tid] = usum * dmp;
  }
  const float dm = (step < OL) ? 1.f : 0.f;
  const float ud = fmaf(mel[((size_t)b*DT + step)*D + tid], dm, usum);

  // ---- stage conv windows: score = masked raw/Z ; cum = cum_old + score ----
  if (tid < 96) {
    int ix = t0 + tid; if (ix > PT-1) ix = PT-1;
    float rv = raw_p[ix];
    float sc = (ix < L + PAD) ? rv * Zinv : 0.f;   // mask AFTER softmax (ref order)
    s_pa[tid] = sc;
    s_pc[tid] = cum_p[ix] + sc;
  }

  // per-lane weights straight from global (coalesced, L2-hot, no reuse in-block)
  float wr[62];
#pragma unroll
  for (int k = 0; k < 62; ++k) wr[k] = WT[k*D + tid];
  __syncthreads();

  // ---- conv + tanh + v-dot; lane = d, t sequential; SGPR window + prefetch ----
  int swa[32], swc[32];
#pragma unroll
  for (int k = 0; k < 31; ++k) { swa[k] = rfl_f(s_pa[k]); swc[k] = rfl_f(s_pc[k]); }
  float nA = s_pa[31], nC = s_pc[31];   // prefetched slide value

#pragma unroll 1
  for (int tb = 0; tb < 64; tb += 32) {
#pragma unroll
    for (int m = 0; m < 32; ++m) {
      const int j = tb + m;
      float s0 = ud, s1 = 0.f, s2 = 0.f, s3 = 0.f;
#pragma unroll
      for (int k = 0; k < 15; ++k) {
        s0 = fmaf(wr[2*k],      __int_as_float(swa[(m+2*k)&31]),   s0);
        s1 = fmaf(wr[2*k+1],    __int_as_float(swa[(m+2*k+1)&31]), s1);
        s2 = fmaf(wr[31+2*k],   __int_as_float(swc[(m+2*k)&31]),   s2);
        s3 = fmaf(wr[31+2*k+1], __int_as_float(swc[(m+2*k+1)&31]), s3);
      }
      s0 = fmaf(wr[30], __int_as_float(swa[(m+30)&31]), s0);
      s2 = fmaf(wr[61], __int_as_float(swc[(m+30)&31]), s2);
      float s = (s0 + s1) + (s2 + s3);
      float ex = __builtin_amdgcn_exp2f(s * (2.f*LOG2E));
      float r  = __builtin_amdgcn_rcpf(ex + 1.f);
      float y  = fmaf(m2v, r, vd);
      y = dpp_add<0xB1>(y);   // + lane^1
      y = dpp_add<0x4E>(y);   // + lane^2
      y = dpp_add<0x141>(y);  // row_half_mirror
      y = dpp_add<0x140>(y);  // row_mirror
      if ((lane & 15) == 0) s_part[j][(wq << 2) | (lane >> 4)] = y;
      // slide with 1-iteration prefetch: ds_read latency hides under FMA chain
      swa[(m+31)&31] = rfl_f(nA);
      swc[(m+31)&31] = rfl_f(nC);
      nA = s_pa[j + 32];            // j+32 <= 95
      nC = s_pc[j + 32];
    }
  }
  __syncthreads();

  // ---- energies -> raw exp (NO max-sub: |e| <= ~12); publish; owner updates ----
  if (tid < 64) {
    const float4 r0 = *(const float4*)&s_part[tid][0];
    const float4 r1 = *(const float4*)&s_part[tid][4];
    const float4 r2 = *(const float4*)&s_part[tid][8];
    const float4 r3 = *(const float4*)&s_part[tid][12];
    float e = (((r0.x+r0.y)+(r0.z+r0.w)) + ((r1.x+r1.y)+(r1.z+r1.w)))
            + (((r2.x+r2.y)+(r2.z+r2.w)) + ((r3.x+r3.y)+(r3.z+r3.w)));
    float raw = __builtin_amdgcn_exp2f(e * LOG2E);
    const int t = t0 + tid;
    raw_n[PAD + t] = raw;                         // raw score state
    s_sc[tid] = (t < L) ? raw : 0.f;              // masked raw for PV
    float ts = raw;                               // tile sum over ALL t (softmax denom)
#pragma unroll
    for (int msk = 1; msk < 64; msk <<= 1) ts += __shfl_xor(ts, msk, 64);
    if (tid == 0) S_n[tile] = ts;
    cum_n[PAD + t] = s_pc[tid + 15];              // cum through step-1 (owner slice)
    if (step > 0)
      out_sc[((size_t)b*DT + step-1)*ET + t] = s_pa[tid + 15];  // delayed score write
  }
  __syncthreads();

  // ---- PV with raw scores (normalized at consumption next step) ----
  if (t0 < L) {
    const float* eb = enc + ((size_t)b*ET + t0)*D + tid;
    float a0 = 0.f, a1 = 0.f, a2 = 0.f, a3 = 0.f;
    for (int r = 0; r < 64; r += 4) {
      a0 = fmaf(s_sc[r],   eb[(size_t)r*D],     a0);
      a1 = fmaf(s_sc[r+1], eb[(size_t)(r+1)*D], a1);
      a2 = fmaf(s_sc[r+2], eb[(size_t)(r+2)*D], a2);
      a3 = fmaf(s_sc[r+3], eb[(size_t)(r+3)*D], a3);
    }
    part_n[tile*D + tid] = (a0 + a1) + (a2 + a3);
  }
}

// epilogue: normalize+write outputs of the final step
__global__ __launch_bounds__(256) void k_fin(
    const int* __restrict__ elen, const int* __restrict__ olen,
    const float* __restrict__ ws,
    float* __restrict__ out_att, float* __restrict__ out_sc) {
  const int tid = threadIdx.x;
  const int bid = blockIdx.x;
  const int xcd = bid & 7, slot = bid >> 3;
  const int b = ((slot & 3) << 3) | xcd;
  const int tile = slot >> 2;
  const int t0 = tile * 64;
  const int p = DT & 1;   // parity holding step DT-1's published state

  const float* raw_p = ws + PBUF_OFF + (size_t)b*4*PT + (size_t)(p*2)*PT;
  const float* part_p = ws + PART_OFF + ((size_t)b*2 + p)*16*D;
  const float* S_p = ws + SSUM_OFF + (b*2 + p)*16;
  const int L = elen[b];
  const int OL = olen[b];

  float z = 0.f;
#pragma unroll
  for (int j = 0; j < 16; ++j) z += S_p[j];
  const float Zinv = 1.f / z;

  if (tile == 0) {
    float usum = 0.f;
#pragma unroll
    for (int j = 0; j < 16; ++j) usum += part_p[j*D + tid];
    float dmp = (DT-1 < OL) ? 1.f : 0.f;
    out_att[((size_t)b*DT + DT-1)*D + tid] = usum * Zinv * dmp;
  }
  if (tid < 64) {
    const int t = t0 + tid;
    float rv = raw_p[PAD + t];
    out_sc[((size_t)b*DT + DT-1)*ET + t] = (t < L) ? rv * Zinv : 0.f;
  }
}

extern "C" void kernel_launch(void* const* d_in, const int* in_sizes, int n_in,
                              void* d_out, int out_size, void* d_ws, size_t ws_size,
                              hipStream_t stream) {
  const float* enc = (const float*)d_in[0];
  const float* mel = (const float*)d_in[1];
  const int* elen  = (const int*)d_in[2];
  const int* olen  = (const int*)d_in[3];
  const float* vw  = (const float*)d_in[4];   // [1, D]
  const float* W   = (const float*)d_in[5];   // [D, 2, KW]

  float* out_att = (float*)d_out;                 // [B, DT, D]
  float* out_sc  = out_att + (size_t)B*DT*D;      // [B, DT, ET]
  float* ws = (float*)d_ws;

  k_init<<<128, 256, 0, stream>>>(W, ws);
  for (int step = 0; step < DT; ++step)
    k_step<<<512, 256, 0, stream>>>(enc, mel, elen, olen, vw, ws,
                                    out_att, out_sc, step);
  k_fin<<<512, 256, 0, stream>>>(elen, olen, ws, out_att, out_sc);
}

// Round 12
// 23725.661 us; speedup vs baseline: 2.6294x; 1.0906x over previous
//
#include <hip/hip_runtime.h>
#include <cstdint>

constexpr int B = 32, ET = 1024, DT = 1024, D = 256, PAD = 15, PT = ET + 2*PAD;
constexpr int NT = 32;                 // 32 t-tiles of 32 per batch
constexpr float LOG2E = 1.4426950408889634f;

// ws float layout (double-buffered by step parity; NO atomics, NO barriers)
constexpr size_t PBUF_OFF = 0;                            // [B][2 par][2 ch][PT] ch0=raw, ch1=cum
constexpr size_t PART_OFF = PBUF_OFF + (size_t)B*4*PT;    // [B][2 par][NT][D] raw PV partials
constexpr size_t SSUM_OFF = PART_OFF + (size_t)B*2*NT*D;  // [B][2 par][NT] raw tile sums
constexpr size_t WP_OFF   = SSUM_OFF + (size_t)B*2*NT;    // [31][D] float2 pairs {Wa[k],Wc[k]}

__global__ __launch_bounds__(256) void k_init(const float* __restrict__ W,
                                              float* __restrict__ ws) {
  int i0 = blockIdx.x*256 + threadIdx.x;
  int stride = gridDim.x*256;
  for (int i = i0; i < B*4*PT; i += stride) ws[PBUF_OFF + i] = 0.f;
  for (int i = i0; i < B*2*NT*D; i += stride) ws[PART_OFF + i] = 0.f;
  for (int i = i0; i < B*2*NT; i += stride) ws[SSUM_OFF + i] = 1.f/NT;  // Z(step0)=1
  for (int i = i0; i < 31*D; i += stride) {   // WP[k][d] = {W[d][k], W[d][31+k]}
    int k = i >> 8, d = i & 255;
    ws[WP_OFF + 2*i]     = W[d*62 + k];
    ws[WP_OFF + 2*i + 1] = W[d*62 + 31 + k];
  }
}

template <int CTRL>
__device__ __forceinline__ float dpp_add(float x) {
  int y = __builtin_amdgcn_update_dpp(0, __float_as_int(x), CTRL, 0xF, 0xF, false);
  return x + __int_as_float(y);
}
__device__ __forceinline__ int rfl_f(float v) {
  return __builtin_amdgcn_readfirstlane(__float_as_int(v));
}

// One decoder step. Reads parity p state (published by step-1), writes parity p^1.
// Kernel boundary provides all cross-block synchronization.
__global__ __attribute__((amdgpu_flat_work_group_size(256, 256), amdgpu_waves_per_eu(2, 4)))
void k_step(
    const float* __restrict__ enc,   // [B][ET][D]
    const float* __restrict__ mel,   // [B][DT][D]
    const int* __restrict__ elen, const int* __restrict__ olen,
    const float* __restrict__ vw,    // [D]
    float* __restrict__ ws,
    float* __restrict__ out_att,     // [B][DT][D]
    float* __restrict__ out_sc,      // [B][DT][ET]
    int step) {
  const int tid = threadIdx.x;                              // d = tid
  const int lane = tid & 63;
  const int wq = __builtin_amdgcn_readfirstlane(tid >> 6);  // wave id 0..3
  const int bid = blockIdx.x;
  const int xcd = bid & 7, slot = bid >> 3;                 // slot 0..127
  const int b = ((slot & 3) << 3) | xcd;                    // L2-locality heuristic
  const int tile = slot >> 2;                               // 0..31
  const int t0 = tile * 32;
  const int p = step & 1, np = p ^ 1;

  float* pb = ws + PBUF_OFF + (size_t)b*4*PT;
  const float* raw_p = pb + (size_t)(p*2 + 0)*PT;
  const float* cum_p = pb + (size_t)(p*2 + 1)*PT;
  float* raw_n = pb + (size_t)(np*2 + 0)*PT;
  float* cum_n = pb + (size_t)(np*2 + 1)*PT;
  const float* part_p = ws + PART_OFF + ((size_t)b*2 + p)*NT*D;
  float*       part_n = ws + PART_OFF + ((size_t)b*2 + np)*NT*D;
  const float* S_p = ws + SSUM_OFF + (b*2 + p)*NT;
  float*       S_n = ws + SSUM_OFF + (b*2 + np)*NT;
  const float2* WP = (const float2*)(ws + WP_OFF);

  __shared__ float s_pa[64], s_pc[64], s_sc[NT];
  __shared__ __align__(16) float s_part[NT][20];

  const int L = elen[b];
  const int OL = olen[b];
  const float vd  = vw[tid];
  const float m2v = -2.f * vd;     // sum_d v*tanh = sum_d (v + m2v*rcp(exp+1))

  // ---- normalization of step-1 state ----
  float z = 0.f;
#pragma unroll
  for (int j = 0; j < NT; ++j) z += S_p[j];
  const float Zinv = 1.f / z;

  // u[d=tid] = mel*dm + att_out(step-1);  att_out = (sum part~)/Z
  float usum = 0.f;
#pragma unroll
  for (int j = 0; j < NT; ++j) usum += part_p[j*D + tid];
  usum *= Zinv;
  if (tile == 0 && step > 0) {
    float dmp = (step-1 < OL) ? 1.f : 0.f;
    out_att[((size_t)b*DT + step-1)*D + tid] = usum * dmp;
  }
  const float dm = (step < OL) ? 1.f : 0.f;
  const float ud = fmaf(mel[((size_t)b*DT + step)*D + tid], dm, usum);

  // ---- stage conv windows: score = masked raw/Z ; cum = cum_old + score ----
  if (tid < 64) {
    int ix = t0 + tid; if (ix > PT-1) ix = PT-1;
    float rv = raw_p[ix];
    float sc = (ix < L + PAD) ? rv * Zinv : 0.f;   // mask AFTER softmax (ref order)
    s_pa[tid] = sc;
    s_pc[tid] = cum_p[ix] + sc;
  }

  // per-lane weights from global, float2-paired (31 dwordx2, coalesced, L2-hot)
  float2 wp[31];
#pragma unroll
  for (int k = 0; k < 31; ++k) wp[k] = WP[k*D + tid];
  __syncthreads();

  // ---- conv + tanh + v-dot; lane = d, t sequential; SGPR window + prefetch ----
  int swa[32], swc[32];
#pragma unroll
  for (int k = 0; k < 31; ++k) { swa[k] = rfl_f(s_pa[k]); swc[k] = rfl_f(s_pc[k]); }
  float nA = s_pa[31], nC = s_pc[31];   // prefetched slide value

#pragma unroll
  for (int m = 0; m < 32; ++m) {
    float s0 = ud, s1 = 0.f, s2 = 0.f, s3 = 0.f;
#pragma unroll
    for (int k = 0; k < 15; ++k) {
      s0 = fmaf(wp[2*k].x,   __int_as_float(swa[(m+2*k)&31]),   s0);
      s1 = fmaf(wp[2*k+1].x, __int_as_float(swa[(m+2*k+1)&31]), s1);
      s2 = fmaf(wp[2*k].y,   __int_as_float(swc[(m+2*k)&31]),   s2);
      s3 = fmaf(wp[2*k+1].y, __int_as_float(swc[(m+2*k+1)&31]), s3);
    }
    s0 = fmaf(wp[30].x, __int_as_float(swa[(m+30)&31]), s0);
    s2 = fmaf(wp[30].y, __int_as_float(swc[(m+30)&31]), s2);
    float s = (s0 + s1) + (s2 + s3);
    float ex = __builtin_amdgcn_exp2f(s * (2.f*LOG2E));
    float r  = __builtin_amdgcn_rcpf(ex + 1.f);
    float y  = fmaf(m2v, r, vd);
    y = dpp_add<0xB1>(y);   // + lane^1
    y = dpp_add<0x4E>(y);   // + lane^2
    y = dpp_add<0x141>(y);  // row_half_mirror
    y = dpp_add<0x140>(y);  // row_mirror
    if ((lane & 15) == 0) s_part[m][(wq << 2) | (lane >> 4)] = y;
    // slide with 1-iteration prefetch: ds_read latency hides under FMA chain
    swa[(m+31)&31] = rfl_f(nA);
    swc[(m+31)&31] = rfl_f(nC);
    nA = s_pa[m + 32];            // m+32 <= 63
    nC = s_pc[m + 32];
  }
  __syncthreads();

  // ---- energies -> raw exp (NO max-sub: |e| <= ~12); publish ----
  if (tid < NT) {
    const float4 r0 = *(const float4*)&s_part[tid][0];
    const float4 r1 = *(const float4*)&s_part[tid][4];
    const float4 r2 = *(const float4*)&s_part[tid][8];
    const float4 r3 = *(const float4*)&s_part[tid][12];
    float e = (((r0.x+r0.y)+(r0.z+r0.w)) + ((r1.x+r1.y)+(r1.z+r1.w)))
            + (((r2.x+r2.y)+(r2.z+r2.w)) + ((r3.x+r3.y)+(r3.z+r3.w)));
    float raw = __builtin_amdgcn_exp2f(e * LOG2E);
    const int t = t0 + tid;
    raw_n[PAD + t] = raw;                         // raw score state
    s_sc[tid] = (t < L) ? raw : 0.f;              // masked raw for PV
    float ts = raw;                               // tile sum over ALL t (denominator)
#pragma unroll
    for (int msk = 1; msk < NT; msk <<= 1) ts += __shfl_xor(ts, msk, 64);
    if (tid == 0) S_n[tile] = ts;
    cum_n[PAD + t] = s_pc[tid + 15];              // cum through step-1 (owner slice)
    if (step > 0)
      out_sc[((size_t)b*DT + step-1)*ET + t] = s_pa[tid + 15];  // delayed score write
  }
  __syncthreads();

  // ---- PV with raw scores (normalized at consumption next step) ----
  if (t0 < L) {
    const float* eb = enc + ((size_t)b*ET + t0)*D + tid;
    float a0 = 0.f, a1 = 0.f, a2 = 0.f, a3 = 0.f;
    for (int r = 0; r < 32; r += 4) {
      a0 = fmaf(s_sc[r],   eb[(size_t)r*D],     a0);
      a1 = fmaf(s_sc[r+1], eb[(size_t)(r+1)*D], a1);
      a2 = fmaf(s_sc[r+2], eb[(size_t)(r+2)*D], a2);
      a3 = fmaf(s_sc[r+3], eb[(size_t)(r+3)*D], a3);
    }
    part_n[tile*D + tid] = (a0 + a1) + (a2 + a3);
  }
}

// epilogue: normalize+write outputs of the final step
__global__ __launch_bounds__(256) void k_fin(
    const int* __restrict__ elen, const int* __restrict__ olen,
    const float* __restrict__ ws,
    float* __restrict__ out_att, float* __restrict__ out_sc) {
  const int tid = threadIdx.x;
  const int bid = blockIdx.x;
  const int xcd = bid & 7, slot = bid >> 3;
  const int b = ((slot & 3) << 3) | xcd;
  const int tile = slot >> 2;
  const int t0 = tile * 32;
  const int p = DT & 1;   // parity holding step DT-1's published state

  const float* raw_p = ws + PBUF_OFF + (size_t)b*4*PT + (size_t)(p*2)*PT;
  const float* part_p = ws + PART_OFF + ((size_t)b*2 + p)*NT*D;
  const float* S_p = ws + SSUM_OFF + (b*2 + p)*NT;
  const int L = elen[b];
  const int OL = olen[b];

  float z = 0.f;
#pragma unroll
  for (int j = 0; j < NT; ++j) z += S_p[j];
  const float Zinv = 1.f / z;

  if (tile == 0) {
    float usum = 0.f;
#pragma unroll
    for (int j = 0; j < NT; ++j) usum += part_p[j*D + tid];
    float dmp = (DT-1 < OL) ? 1.f : 0.f;
    out_att[((size_t)b*DT + DT-1)*D + tid] = usum * Zinv * dmp;
  }
  if (tid < 32) {
    const int t = t0 + tid;
    float rv = raw_p[PAD + t];
    out_sc[((size_t)b*DT + DT-1)*ET + t] = (t < L) ? rv * Zinv : 0.f;
  }
}

extern "C" void kernel_launch(void* const* d_in, const int* in_sizes, int n_in,
                              void* d_out, int out_size, void* d_ws, size_t ws_size,
                              hipStream_t stream) {
  const float* enc = (const float*)d_in[0];
  const float* mel = (const float*)d_in[1];
  const int* elen  = (const int*)d_in[2];
  const int* olen  = (const int*)d_in[3];
  const float* vw  = (const float*)d_in[4];   // [1, D]
  const float* W   = (const float*)d_in[5];   // [D, 2, KW]

  float* out_att = (float*)d_out;                 // [B, DT, D]
  float* out_sc  = out_att + (size_t)B*DT*D;      // [B, DT, ET]
  float* ws = (float*)d_ws;

  k_init<<<128, 256, 0, stream>>>(W, ws);
  for (int step = 0; step < DT; ++step)
    k_step<<<1024, 256, 0, stream>>>(enc, mel, elen, olen, vw, ws,
                                     out_att, out_sc, step);
  k_fin<<<1024, 256, 0, stream>>>(elen, olen, ws, out_att, out_sc);
}

// Round 13
// 8396.466 us; speedup vs baseline: 7.4298x; 2.8257x over previous
//
#include <hip/hip_runtime.h>
#include <cstdint>

constexpr int B = 32, ET = 1024, DT = 1024, D = 256, PAD = 15, PT = ET + 2*PAD;
constexpr int NT = 32;                 // 32 t-tiles of 32 per batch
constexpr float LOG2E = 1.4426950408889634f;

typedef __attribute__((ext_vector_type(4))) float f32x4;
typedef __attribute__((ext_vector_type(4))) unsigned int uint4v;
typedef __attribute__((ext_vector_type(8))) __bf16 bf16x8;

// ws float layout (double-buffered by step parity; NO atomics, NO barriers)
constexpr size_t PBUF_OFF = 0;                            // [B][2 par][2 ch][PT] ch0=raw, ch1=cum
constexpr size_t PART_OFF = PBUF_OFF + (size_t)B*4*PT;    // [B][2 par][NT][D] raw PV partials
constexpr size_t SSUM_OFF = PART_OFF + (size_t)B*2*NT*D;  // [B][2 par][NT] raw tile sums
constexpr size_t WF_OFF   = SSUM_OFF + (size_t)B*2*NT;    // A-frag table, 16384 floats:
// [16 dtile][2 ch][2 split][64 lane][8 bf16]  (A[d][k]: lane = (d&15) + 16*(k/8), elem = k%8)

__global__ __launch_bounds__(256) void k_init(const float* __restrict__ W,
                                              float* __restrict__ ws) {
  int i0 = blockIdx.x*256 + threadIdx.x;
  int stride = gridDim.x*256;
  for (int i = i0; i < B*4*PT; i += stride) ws[PBUF_OFF + i] = 0.f;
  for (int i = i0; i < B*2*NT*D; i += stride) ws[PART_OFF + i] = 0.f;
  for (int i = i0; i < B*2*NT; i += stride) ws[SSUM_OFF + i] = 1.f/NT;  // Z(step0)=1
  // A-fragment table: hi/lo bf16 (truncation split) of W, zero-padded tap 31
  for (int i = i0; i < 16*2*2*64*8; i += stride) {
    int j = i & 7, lane = (i >> 3) & 63, split = (i >> 9) & 1,
        ch = (i >> 10) & 1, dt = i >> 11;
    int d = dt*16 + (lane & 15);
    int koff = (lane >> 4)*8 + j;
    float val = (koff < 31) ? W[d*62 + ch*31 + koff] : 0.f;
    unsigned bits = __float_as_uint(val);
    unsigned hb = bits & 0xFFFF0000u;
    unsigned half;
    if (split == 0) half = bits >> 16;
    else            half = __float_as_uint(val - __uint_as_float(hb)) >> 16;
    ((unsigned short*)(ws + WF_OFF))[i] = (unsigned short)half;
  }
}

__device__ __forceinline__ f32x4 mfma16(uint4v a, uint4v b, f32x4 c) {
  return __builtin_amdgcn_mfma_f32_16x16x32_bf16(
      __builtin_bit_cast(bf16x8, a), __builtin_bit_cast(bf16x8, b), c, 0, 0, 0);
}

// One decoder step. Reads parity p state (published by step-1), writes parity p^1.
// Kernel boundary provides all cross-block synchronization.
__global__ __attribute__((amdgpu_flat_work_group_size(256, 256), amdgpu_waves_per_eu(2, 4)))
void k_step(
    const float* __restrict__ enc,   // [B][ET][D]
    const float* __restrict__ mel,   // [B][DT][D]
    const int* __restrict__ elen, const int* __restrict__ olen,
    const float* __restrict__ vw,    // [D]
    float* __restrict__ ws,
    float* __restrict__ out_att,     // [B][DT][D]
    float* __restrict__ out_sc,      // [B][DT][ET]
    int step) {
  const int tid = threadIdx.x;
  const int lane = tid & 63;
  const int wq = __builtin_amdgcn_readfirstlane(tid >> 6);  // wave id 0..3
  const int bid = blockIdx.x;
  const int xcd = bid & 7, slot = bid >> 3;                 // slot 0..127
  const int b = ((slot & 3) << 3) | xcd;                    // L2-locality heuristic
  const int tile = slot >> 2;                               // 0..31
  const int t0 = tile * 32;
  const int p = step & 1, np = p ^ 1;

  float* pb = ws + PBUF_OFF + (size_t)b*4*PT;
  const float* raw_p = pb + (size_t)(p*2 + 0)*PT;
  const float* cum_p = pb + (size_t)(p*2 + 1)*PT;
  float* raw_n = pb + (size_t)(np*2 + 0)*PT;
  float* cum_n = pb + (size_t)(np*2 + 1)*PT;
  const float* part_p = ws + PART_OFF + ((size_t)b*2 + p)*NT*D;
  float*       part_n = ws + PART_OFF + ((size_t)b*2 + np)*NT*D;
  const float* S_p = ws + SSUM_OFF + (b*2 + p)*NT;
  float*       S_n = ws + SSUM_OFF + (b*2 + np)*NT;

  __shared__ float s_pa[64], s_pc[64], s_sc[NT];
  __shared__ __align__(16) float u_lds[256], v_lds[256];
  __shared__ __align__(16) float s_part[NT][20];

  const int L = elen[b];
  const int OL = olen[b];

  // ---- normalization of step-1 state ----
  float z = 0.f;
#pragma unroll
  for (int j = 0; j < NT; ++j) z += S_p[j];
  const float Zinv = 1.f / z;

  // u[d=tid] = mel*dm + att_out(step-1);  att_out = (sum part~)/Z
  float usum = 0.f;
#pragma unroll
  for (int j = 0; j < NT; ++j) usum += part_p[j*D + tid];
  usum *= Zinv;
  if (tile == 0 && step > 0) {
    float dmp = (step-1 < OL) ? 1.f : 0.f;
    out_att[((size_t)b*DT + step-1)*D + tid] = usum * dmp;
  }
  const float dm = (step < OL) ? 1.f : 0.f;
  u_lds[tid] = fmaf(mel[((size_t)b*DT + step)*D + tid], dm, usum); // u[d=tid]
  v_lds[tid] = vw[tid];

  // ---- stage conv windows: score = masked raw/Z ; cum = cum_old + score ----
  // s_pa[x] = p_abs[t0 + x - 15] via the halo-padded buffer
  if (tid < 64) {
    int ix = t0 + tid; if (ix > PT-1) ix = PT-1;
    float rv = raw_p[ix];
    float sc = (ix < L + PAD) ? rv * Zinv : 0.f;   // mask AFTER softmax (ref order)
    s_pa[tid] = sc;
    s_pc[tid] = cum_p[ix] + sc;
  }
  __syncthreads();

  // ---- phase 1b: conv via MFMA (split-bf16), then tanh + v-dot epilogue ----
  // B[k][t'] per channel: value = window[t' + k] (k=31 -> 0). Layout:
  // lane = t' + 16*(k/8), elem = k%8.
  uint4v Bf[2][2][2];   // [tt][ch][split]
  {
    const int tq = lane >> 4, tc = lane & 15;
#pragma unroll
    for (int tt = 0; tt < 2; ++tt)
#pragma unroll
      for (int ch = 0; ch < 2; ++ch) {
        const float* src = ch ? s_pc : s_pa;
        const int base = tt*16 + tc;
#pragma unroll
        for (int jj = 0; jj < 4; ++jj) {
          unsigned hpair = 0, lpair = 0;
#pragma unroll
          for (int h = 0; h < 2; ++h) {
            int koff = tq*8 + jj*2 + h;
            float x = (koff < 31) ? src[base + koff] : 0.f;
            unsigned bits = __float_as_uint(x);
            unsigned hb = bits & 0xFFFF0000u;
            unsigned lb = __float_as_uint(x - __uint_as_float(hb));
            hpair |= (bits >> 16) << (16*h);
            lpair |= (lb >> 16) << (16*h);
          }
          Bf[tt][ch][0][jj] = hpair;
          Bf[tt][ch][1][jj] = lpair;
        }
      }
  }

  const uint4v* ap = (const uint4v*)(ws + WF_OFF);
  float ep0 = 0.f, ep1 = 0.f;
#pragma unroll
  for (int dti = 0; dti < 4; ++dti) {
    const int dt = wq*4 + dti;      // this wave's d-tile (16 d rows)
    uint4v a0h = ap[((dt*2 + 0)*2 + 0)*64 + lane];   // ch0 hi
    uint4v a0l = ap[((dt*2 + 0)*2 + 1)*64 + lane];   // ch0 lo
    uint4v a1h = ap[((dt*2 + 1)*2 + 0)*64 + lane];   // ch1 hi
    uint4v a1l = ap[((dt*2 + 1)*2 + 1)*64 + lane];   // ch1 lo
    const int du = dt*16 + (lane >> 4)*4;            // C rows this lane holds
    f32x4 u4 = *(const f32x4*)&u_lds[du];
    f32x4 v4 = *(const f32x4*)&v_lds[du];
#pragma unroll
    for (int tt = 0; tt < 2; ++tt) {
      f32x4 acc = {0.f, 0.f, 0.f, 0.f};
      acc = mfma16(a0h, Bf[tt][0][0], acc);   // hi*hi ch0
      acc = mfma16(a0l, Bf[tt][0][0], acc);   // lo*hi ch0
      acc = mfma16(a0h, Bf[tt][0][1], acc);   // hi*lo ch0
      acc = mfma16(a1h, Bf[tt][1][0], acc);   // hi*hi ch1
      acc = mfma16(a1l, Bf[tt][1][0], acc);   // lo*hi ch1
      acc = mfma16(a1h, Bf[tt][1][1], acc);   // hi*lo ch1
      float ep = 0.f;
#pragma unroll
      for (int r = 0; r < 4; ++r) {
        float s = acc[r] + u4[r];
        // v*tanh(s), tanh(s) = 1 - 2/(exp(2s)+1)
        float ex = __builtin_amdgcn_exp2f(s * (2.f*LOG2E));
        float th = fmaf(-2.f, __builtin_amdgcn_rcpf(ex + 1.f), 1.f);
        ep = fmaf(v4[r], th, ep);
      }
      if (tt == 0) ep0 += ep; else ep1 += ep;
    }
  }
  // partial energies: 16 per t (4 waves x 4 row-quads), same reduce as before
  s_part[lane & 15][(wq << 2) | (lane >> 4)] = ep0;
  s_part[16 + (lane & 15)][(wq << 2) | (lane >> 4)] = ep1;
  __syncthreads();

  // ---- energies -> raw exp (NO max-sub: |e| <= sum|v| ~12); publish ----
  if (tid < NT) {
    const float4 r0 = *(const float4*)&s_part[tid][0];
    const float4 r1 = *(const float4*)&s_part[tid][4];
    const float4 r2 = *(const float4*)&s_part[tid][8];
    const float4 r3 = *(const float4*)&s_part[tid][12];
    float e = (((r0.x+r0.y)+(r0.z+r0.w)) + ((r1.x+r1.y)+(r1.z+r1.w)))
            + (((r2.x+r2.y)+(r2.z+r2.w)) + ((r3.x+r3.y)+(r3.z+r3.w)));
    float raw = __builtin_amdgcn_exp2f(e * LOG2E);
    const int t = t0 + tid;
    raw_n[PAD + t] = raw;                         // raw score state
    s_sc[tid] = (t < L) ? raw : 0.f;              // masked raw for PV
    float ts = raw;                               // tile sum over ALL t (denominator)
#pragma unroll
    for (int msk = 1; msk < NT; msk <<= 1) ts += __shfl_xor(ts, msk, 64);
    if (tid == 0) S_n[tile] = ts;
    cum_n[PAD + t] = s_pc[tid + 15];              // cum through step-1 (owner slice)
    if (step > 0)
      out_sc[((size_t)b*DT + step-1)*ET + t] = s_pa[tid + 15];  // delayed score write
  }
  __syncthreads();

  // ---- PV with raw scores (normalized at consumption next step) ----
  if (t0 < L) {
    const float* eb = enc + ((size_t)b*ET + t0)*D + tid;
    float a0 = 0.f, a1 = 0.f, a2 = 0.f, a3 = 0.f;
    for (int r = 0; r < 32; r += 4) {
      a0 = fmaf(s_sc[r],   eb[(size_t)r*D],     a0);
      a1 = fmaf(s_sc[r+1], eb[(size_t)(r+1)*D], a1);
      a2 = fmaf(s_sc[r+2], eb[(size_t)(r+2)*D], a2);
      a3 = fmaf(s_sc[r+3], eb[(size_t)(r+3)*D], a3);
    }
    part_n[tile*D + tid] = (a0 + a1) + (a2 + a3);
  }
}

// epilogue: normalize+write outputs of the final step
__global__ __launch_bounds__(256) void k_fin(
    const int* __restrict__ elen, const int* __restrict__ olen,
    const float* __restrict__ ws,
    float* __restrict__ out_att, float* __restrict__ out_sc) {
  const int tid = threadIdx.x;
  const int bid = blockIdx.x;
  const int xcd = bid & 7, slot = bid >> 3;
  const int b = ((slot & 3) << 3) | xcd;
  const int tile = slot >> 2;
  const int t0 = tile * 32;
  const int p = DT & 1;   // parity holding step DT-1's published state

  const float* raw_p = ws + PBUF_OFF + (size_t)b*4*PT + (size_t)(p*2)*PT;
  const float* part_p = ws + PART_OFF + ((size_t)b*2 + p)*NT*D;
  const float* S_p = ws + SSUM_OFF + (b*2 + p)*NT;
  const int L = elen[b];
  const int OL = olen[b];

  float z = 0.f;
#pragma unroll
  for (int j = 0; j < NT; ++j) z += S_p[j];
  const float Zinv = 1.f / z;

  if (tile == 0) {
    float usum = 0.f;
#pragma unroll
    for (int j = 0; j < NT; ++j) usum += part_p[j*D + tid];
    float dmp = (DT-1 < OL) ? 1.f : 0.f;
    out_att[((size_t)b*DT + DT-1)*D + tid] = usum * Zinv * dmp;
  }
  if (tid < 32) {
    const int t = t0 + tid;
    float rv = raw_p[PAD + t];
    out_sc[((size_t)b*DT + DT-1)*ET + t] = (t < L) ? rv * Zinv : 0.f;
  }
}

extern "C" void kernel_launch(void* const* d_in, const int* in_sizes, int n_in,
                              void* d_out, int out_size, void* d_ws, size_t ws_size,
                              hipStream_t stream) {
  const float* enc = (const float*)d_in[0];
  const float* mel = (const float*)d_in[1];
  const int* elen  = (const int*)d_in[2];
  const int* olen  = (const int*)d_in[3];
  const float* vw  = (const float*)d_in[4];   // [1, D]
  const float* W   = (const float*)d_in[5];   // [D, 2, KW]

  float* out_att = (float*)d_out;                 // [B, DT, D]
  float* out_sc  = out_att + (size_t)B*DT*D;      // [B, DT, ET]
  float* ws = (float*)d_ws;

  k_init<<<128, 256, 0, stream>>>(W, ws);
  for (int step = 0; step < DT; ++step)
    k_step<<<1024, 256, 0, stream>>>(enc, mel, elen, olen, vw, ws,
                                     out_att, out_sc, step);
  k_fin<<<1024, 256, 0, stream>>>(elen, olen, ws, out_att, out_sc);
}